// Round 10
// baseline (345.488 us; speedup 1.0000x reference)
//
#include <hip/hip_runtime.h>
#include <math.h>

typedef __bf16 bf16_t;
typedef bf16_t bf16x4 __attribute__((ext_vector_type(4)));
typedef bf16_t bf16x8 __attribute__((ext_vector_type(8)));
typedef float  f32x16 __attribute__((ext_vector_type(16)));

#define HH 1024
#define CC 8
#define DD 64
#define FF 32
#define WW 7
#define HP 1018
#define HPAD 1024
#define NF 128
#define QOUT (NF*HP*DD)
#define QWS ((size_t)NF*HPAD*DD)

#if __has_builtin(__builtin_amdgcn_exp2f)
#define EXP2(x) __builtin_amdgcn_exp2f(x)
#else
#define EXP2(x) __expf((x) * 0.6931471805599453f)
#endif

// q1 is pre-scaled by log2(e)/1018 at conv time, so flash computes exp2(S) directly.
#define QSCALE (1.442695040888963f / 1018.f)

// Vt: row stride 64 bf16, XOR-swizzled 8-element chunks (validated R4):
//   addr(row, col) = row*64 + (((col>>3) ^ (row&7) ^ ((row>>2)&7))<<3) + (col&7)
__device__ __forceinline__ int vaddr(int row, int col) {
    return row*64 + ((((col>>3) ^ (row&7) ^ ((row>>2)&7)))<<3) + (col&7);
}

// ---------------- W transpose: Wt[f][c][d][j] -> Wp[f][c][j][d] ----------------
__global__ __launch_bounds__(256) void wprep_kernel(
    const float* __restrict__ Wt, float* __restrict__ Wp)
{
    const int idx = blockIdx.x * 256 + threadIdx.x;
    if (idx < FF*CC*DD*WW) {
        const int j = idx % WW;
        int t = idx / WW;
        const int d = t % DD; t /= DD;
        const int c = t % CC;
        const int f = t / CC;
        Wp[((f*CC + c)*WW + j)*DD + d] = Wt[idx];
    }
}

// ---------------- projection (grouped conv) ----------------
// 16-row h-tiles: staged window 22 rows = 45 KB LDS -> 3 blocks/CU.
// xs identity copy [row][c][d]; compute reads xs[row*512 + c*64 + d]: lanes differ
// only in d -> 2 lanes/bank, conflict-free.
// grid (64, 4, 8): z&1 selects input, z>>1 selects filter pair (2 f/thread).
// (Benched as part of the 207.9 us best config.)
__global__ __launch_bounds__(256, 3) void conv_kernel(
    const float* __restrict__ x1, const float* __restrict__ x2,
    const float* __restrict__ Wp, bf16_t* __restrict__ q1, bf16_t* __restrict__ q2)
{
    __shared__ float xs[22*512];
    const int zin = blockIdx.z & 1;
    const int fh = blockIdx.z >> 1;       // 0..3
    const float* x = zin ? x2 : x1;
    bf16_t* q = zin ? q2 : q1;
    const float qs = zin ? 1.f : QSCALE;  // bake softmax scale into q1
    const int n = blockIdx.y;
    const int hb = blockIdx.x * 16;
    const int tid = threadIdx.x;

    const float4* xg = (const float4*)(x + (size_t)n*HH*512);
    float4* xsv = (float4*)xs;
#pragma unroll
    for (int it = 0; it < 11; ++it) {     // 22*128 / 256 = 11
        const int i = it*256 + tid;
        const int row = hb + (i >> 7);
        float4 v = {0.f, 0.f, 0.f, 0.f};
        if (row < HH) v = xg[(size_t)row*128 + (i & 127)];
        xsv[i] = v;
    }

    const int d = tid & 63;
    const int fq = tid >> 6;

    // weights for this thread's 2 filters, issued before the barrier
    float w[2][CC][WW];
#pragma unroll
    for (int fi = 0; fi < 2; ++fi) {
        const int f = fq*8 + fh*2 + fi;
#pragma unroll
        for (int c = 0; c < CC; ++c)
#pragma unroll
            for (int j = 0; j < WW; ++j)
                w[fi][c][j] = Wp[((f*CC + c)*WW + j)*DD + d];
    }

    __syncthreads();

    float acc[2][16];
#pragma unroll
    for (int fi = 0; fi < 2; ++fi)
#pragma unroll
        for (int i = 0; i < 16; ++i) acc[fi][i] = 0.f;

#pragma unroll
    for (int rr = 0; rr < 22; ++rr) {
        float xv[CC];
#pragma unroll
        for (int c = 0; c < CC; ++c)
            xv[c] = xs[rr*512 + c*64 + d];
#pragma unroll
        for (int fi = 0; fi < 2; ++fi)
#pragma unroll
            for (int j = 0; j < WW; ++j) {
                const int i = rr - j;          // compile-time guard (full unroll)
                if (i >= 0 && i < 16) {
#pragma unroll
                    for (int c = 0; c < CC; ++c)
                        acc[fi][i] = fmaf(xv[c], w[fi][c][j], acc[fi][i]);
                }
            }
    }

#pragma unroll
    for (int fi = 0; fi < 2; ++fi) {
        const int f = fq*8 + fh*2 + fi;
#pragma unroll
        for (int i = 0; i < 16; ++i) {
            const int h = hb + i;
            const float v = (h < HP) ? acc[fi][i]*qs : 0.f;
            q[((size_t)(n*FF + f)*HPAD + h)*DD + d] = (bf16_t)v;
        }
    }
}

__device__ __forceinline__ float fast_tanh(float x) {
    const float t = __expf(2.f * x);
    return (t - 1.f) / (t + 1.f);
}

// One half-tile step. AQ/mtv are literal; pft = tile index to refill AQ[mtv] from.
#define MT_STEP(AQ, mtv, pft) {                                                   \
    f32x16 C[2] = {};                                                             \
    __builtin_amdgcn_s_setprio(1);                                                \
    _Pragma("unroll")                                                             \
    for (int kt = 0; kt < 4; ++kt) {                                              \
        C[0] = __builtin_amdgcn_mfma_f32_32x32x16_bf16(AQ[mtv][kt], bq1[0][kt], C[0], 0,0,0); \
        C[1] = __builtin_amdgcn_mfma_f32_32x32x16_bf16(AQ[mtv][kt], bq1[1][kt], C[1], 0,0,0); \
    }                                                                             \
    __builtin_amdgcn_s_setprio(0);                                                \
    if ((pft) < 16) {   /* refill for tile pft: ~2-tile in-flight window */       \
        _Pragma("unroll")                                                         \
        for (int kt = 0; kt < 4; ++kt)                                            \
            AQ[mtv][kt] = *(const bf16x8*)&ap[(size_t)((pft)*64 + 32*(mtv))*DD + 16*kt]; \
    }                                                                             \
    bf16x8 af[2][2];                                                              \
    _Pragma("unroll")                                                             \
    for (int nt = 0; nt < 2; ++nt) {                                              \
        float ls = 0.f;                                                           \
        _Pragma("unroll")                                                         \
        for (int s = 0; s < 16; ++s) {                                            \
            float e = EXP2(C[nt][s]);                                             \
            if (tail) {                                                           \
                const int gg = g0 + 32*(mtv) + (s&3) + 8*(s>>2) + 4*half;         \
                if (gg >= HP) e = 0.f;                                            \
            }                                                                     \
            ls += e;                                                              \
            af[nt][s>>3][s&7] = (bf16_t)e;                                        \
        }                                                                         \
        lacc[nt] += ls;                                                           \
    }                                                                             \
    __builtin_amdgcn_s_setprio(1);                                                \
    _Pragma("unroll")                                                             \
    for (int u = 0; u < 2; ++u) {                                                 \
        _Pragma("unroll")                                                         \
        for (int dt = 0; dt < 2; ++dt) {                                          \
            const int chunk = (4*(mtv) + 2*u + half) ^ vswz;                      \
            bf16x8 b = *(const bf16x8*)&vtc[(32*dt + lid)*64 + chunk*8];          \
            O[0][dt] = __builtin_amdgcn_mfma_f32_32x32x16_bf16(af[0][u], b, O[0][dt], 0,0,0); \
            O[1][dt] = __builtin_amdgcn_mfma_f32_32x32x16_bf16(af[1][u], b, O[1][dt], 0,0,0); \
        }                                                                         \
    }                                                                             \
    __builtin_amdgcn_s_setprio(0); }

// Full tile: V-stage + two half-tile steps + barrier. tt literal-ish (unrolled x2).
#define TILE_BODY(tt, AQ) {                                                       \
    const int g0 = (tt) << 6;                                                     \
    const bf16_t* vtc = Vt[(tt) & 1];                                             \
    const bool tail = ((tt) == 15);                                               \
    if ((tt) + 1 < 16) {                                                          \
        bf16_t* vtn = Vt[((tt) + 1) & 1];                                         \
        _Pragma("unroll")                                                         \
        for (int j = 0; j < 4; ++j) {                                             \
            bf16x4 c = { rV[0][j], rV[1][j], rV[2][j], rV[3][j] };                \
            *(bf16x4*)&vtn[vaddr(4*dq + j, cgb)] = c;                             \
        }                                                                         \
        if ((tt) + 2 < 16) {                                                      \
            _Pragma("unroll")                                                     \
            for (int i = 0; i < 4; ++i)                                           \
                rV[i] = *(const bf16x4*)&vp[(size_t)(((tt) + 2)*64 + i)*DD + 0];  \
        }                                                                         \
    }                                                                             \
    MT_STEP(AQ, 0, (tt) + 2);                                                     \
    MT_STEP(AQ, 1, (tt) + 2);                                                     \
    __syncthreads(); }

// ---------------- fused flash pass (MFMA), 64 h-rows/wave ----------------
// grid (4, NF), 2 blocks/CU. Vt double-buffered, 1 barrier/tile (57 us base).
// R10 changes (both target LOAD LATENCY):
//  1. XCD-chunked swizzle: wg -> (wg&7)*64 + wg/8 (bijective, 512%8==0). Each XCD
//     gets 16 COMPLETE heads, so a head's 4 h-blocks share one L2 copy of q2/V/p1
//     (was: 4 blocks on 4 XCDs, 4x L2 fill, per-XCD working set > 4MB L2).
//  2. 2-tile aq prefetch ping-pong (aqA even tiles / aqB odd): refill right after
//     each S-phase for tile t+2 -> ~2200 cy in-flight >> 900 cy HBM-miss latency.
//     VGPR budget is grid-limited-free: 2 blocks/CU -> cap 256/wave, state ~220.
template<int MODE>
__global__ __launch_bounds__(256, 2) void flash(
    const bf16_t* __restrict__ q1, const bf16_t* __restrict__ q2,
    const bf16_t* __restrict__ vsrc, bf16_t* __restrict__ p1out,
    float* __restrict__ out)
{
    __shared__ __align__(16) bf16_t Vt[2][64*64];  // V^T tiles [d][p(g)], swizzled

    const int wg = blockIdx.x + 4 * blockIdx.y;    // 512 wgs
    const int swz = (wg & 7) * 64 + (wg >> 3);     // XCD-chunked remap (bijective)
    const int head = swz >> 2;
    const int bx = swz & 3;
    const int n = head >> 5, f = head & 31;
    const int tid = threadIdx.x;
    const int w = tid >> 6;
    const int lane = tid & 63;
    const int lid = lane & 31;
    const int half = lane >> 5;
    const int hb = bx * 256 + w * 64;

    const size_t qoff = (size_t)head * HPAD * DD;
    const int vswz = (lid & 7) ^ (lid >> 2);

    // Vt staging map: thread stages rows g=4gq..4gq+3, cols 4dq..4dq+3
    const int gq = tid >> 4;
    const int dq = tid & 15;
    const int cgb = 4*((gq>>1)&1) + 8*(gq&1) + 16*(gq>>2);   // permuted col base

    const bf16_t* vptr = (MODE == 1) ? vsrc : q2;

    // hoisted per-thread base pointers
    const bf16_t* bp = q1 + qoff + (size_t)(hb + lid)*DD + 8*half;
    const bf16_t* ap = q2 + qoff + (size_t)lid*DD + 8*half;
    const bf16_t* vp = vptr + qoff + (size_t)(4*gq)*DD + 4*dq;

    // Q1 B-fragments, persistent in registers (pre-scaled by QSCALE in conv)
    bf16x8 bq1[2][4];
#pragma unroll
    for (int nt = 0; nt < 2; ++nt)
#pragma unroll
        for (int kt = 0; kt < 4; ++kt)
            bq1[nt][kt] = *(const bf16x8*)&bp[(size_t)(32*nt)*DD + 16*kt];

    // A-fragment ping-pong: aqA <- tile 0, aqB <- tile 1
    bf16x8 aqA[2][4], aqB[2][4];
#pragma unroll
    for (int mt = 0; mt < 2; ++mt)
#pragma unroll
        for (int kt = 0; kt < 4; ++kt) {
            aqA[mt][kt] = *(const bf16x8*)&ap[(size_t)(32*mt)*DD + 16*kt];
            aqB[mt][kt] = *(const bf16x8*)&ap[(size_t)(64 + 32*mt)*DD + 16*kt];
        }

    // V staging regs: tile 0 -> write buffer 0 now; then prefetch tile 1
    bf16x4 rV[4];
#pragma unroll
    for (int i = 0; i < 4; ++i)
        rV[i] = *(const bf16x4*)&vp[(size_t)i*DD];
#pragma unroll
    for (int j = 0; j < 4; ++j) {
        bf16x4 c = { rV[0][j], rV[1][j], rV[2][j], rV[3][j] };
        *(bf16x4*)&Vt[0][vaddr(4*dq + j, cgb)] = c;
    }
#pragma unroll
    for (int i = 0; i < 4; ++i)
        rV[i] = *(const bf16x4*)&vp[(size_t)(64 + i)*DD];

    f32x16 O[2][2] = {};
    float lacc[2] = {0.f, 0.f};

    __syncthreads();                               // Vt[0] ready

    for (int t = 0; t < 16; t += 2) {
        TILE_BODY(t,     aqA);                     // even tile: aqA, refill <- t+2
        TILE_BODY(t + 1, aqB);                     // odd tile:  aqB, refill <- t+3
    }

    // ---- epilogue ----
    float linv[2];
#pragma unroll
    for (int nt = 0; nt < 2; ++nt) {
        const float l = lacc[nt] + __shfl_xor(lacc[nt], 32);
        linv[nt] = 1.f / l;
    }
#pragma unroll
    for (int ht = 0; ht < 2; ++ht) {
#pragma unroll
        for (int s = 0; s < 16; ++s) {
            const int R = (s&3) + 8*(s>>2) + 4*half;
            const float li = __shfl(linv[ht], R);
            const int hg = hb + 32*ht + R;
#pragma unroll
            for (int dt = 0; dt < 2; ++dt) {
                const int d = 32*dt + lid;
                const float val = O[ht][dt][s] * li;
                if (hg < HP)
                    out[(((size_t)n*HP + hg)*FF + f)*DD + d] = fast_tanh(val);
                if (MODE == 0)   // zero-pad p1 rows >= HP so pass B stages clean data
                    p1out[qoff + (size_t)hg*DD + d] = (bf16_t)(hg < HP ? val : 0.f);
            }
        }
    }
}

extern "C" void kernel_launch(void* const* d_in, const int* in_sizes, int n_in,
                              void* d_out, int out_size, void* d_ws, size_t ws_size,
                              hipStream_t stream)
{
    const float* prot1 = (const float*)d_in[0];
    const float* prot2 = (const float*)d_in[1];
    const float* Wt    = (const float*)d_in[2];
    float* out = (float*)d_out;

    bf16_t* q1b = (bf16_t*)d_ws;
    bf16_t* q2b = q1b + QWS;
    bf16_t* p1b = q2b + QWS;
    float* Wp   = (float*)(p1b + QWS);

    wprep_kernel<<<dim3(448), 256, 0, stream>>>(Wt, Wp);
    conv_kernel<<<dim3(64, 4, 8), 256, 0, stream>>>(prot1, prot2, Wp, q1b, q2b);
    flash<0><<<dim3(4, NF), 256, 0, stream>>>(q1b, q2b, q2b, p1b, out);
    flash<1><<<dim3(4, NF), 256, 0, stream>>>(q1b, q2b, p1b, p1b, out + QOUT);
}

// Round 12
// 209.188 us; speedup vs baseline: 1.6516x; 1.6516x over previous
//
#include <hip/hip_runtime.h>
#include <math.h>

typedef __bf16 bf16_t;
typedef bf16_t bf16x4 __attribute__((ext_vector_type(4)));
typedef bf16_t bf16x8 __attribute__((ext_vector_type(8)));
typedef float  f32x16 __attribute__((ext_vector_type(16)));

#define HH 1024
#define CC 8
#define DD 64
#define FF 32
#define WW 7
#define HP 1018
#define HPAD 1024
#define NF 128
#define QOUT (NF*HP*DD)
#define QWS ((size_t)NF*HPAD*DD)

#if __has_builtin(__builtin_amdgcn_exp2f)
#define EXP2(x) __builtin_amdgcn_exp2f(x)
#else
#define EXP2(x) __expf((x) * 0.6931471805599453f)
#endif

// q1 is pre-scaled by log2(e)/1018 at conv time, so flash computes exp2(S) directly.
#define QSCALE (1.442695040888963f / 1018.f)

// Vt: row stride 64 bf16, XOR-swizzled 8-element chunks (validated R4):
//   addr(row, col) = row*64 + (((col>>3) ^ (row&7) ^ ((row>>2)&7))<<3) + (col&7)
__device__ __forceinline__ int vaddr(int row, int col) {
    return row*64 + ((((col>>3) ^ (row&7) ^ ((row>>2)&7)))<<3) + (col&7);
}

// ---------------- W transpose: Wt[f][c][d][j] -> Wp[f][c][j][d] ----------------
__global__ __launch_bounds__(256) void wprep_kernel(
    const float* __restrict__ Wt, float* __restrict__ Wp)
{
    const int idx = blockIdx.x * 256 + threadIdx.x;
    if (idx < FF*CC*DD*WW) {
        const int j = idx % WW;
        int t = idx / WW;
        const int d = t % DD; t /= DD;
        const int c = t % CC;
        const int f = t / CC;
        Wp[((f*CC + c)*WW + j)*DD + d] = Wt[idx];
    }
}

// ---------------- projection (grouped conv) ----------------
// 16-row h-tiles: staged window 22 rows = 45 KB LDS -> 3 blocks/CU.
// xs identity copy [row][c][d]; compute reads xs[row*512 + c*64 + d]: lanes differ
// only in d -> 2 lanes/bank, conflict-free.
// grid (64, 4, 8): z&1 selects input, z>>1 selects filter pair (2 f/thread).
// (Benched as part of the 207.9 us best config.)
__global__ __launch_bounds__(256, 3) void conv_kernel(
    const float* __restrict__ x1, const float* __restrict__ x2,
    const float* __restrict__ Wp, bf16_t* __restrict__ q1, bf16_t* __restrict__ q2)
{
    __shared__ float xs[22*512];
    const int zin = blockIdx.z & 1;
    const int fh = blockIdx.z >> 1;       // 0..3
    const float* x = zin ? x2 : x1;
    bf16_t* q = zin ? q2 : q1;
    const float qs = zin ? 1.f : QSCALE;  // bake softmax scale into q1
    const int n = blockIdx.y;
    const int hb = blockIdx.x * 16;
    const int tid = threadIdx.x;

    const float4* xg = (const float4*)(x + (size_t)n*HH*512);
    float4* xsv = (float4*)xs;
#pragma unroll
    for (int it = 0; it < 11; ++it) {     // 22*128 / 256 = 11
        const int i = it*256 + tid;
        const int row = hb + (i >> 7);
        float4 v = {0.f, 0.f, 0.f, 0.f};
        if (row < HH) v = xg[(size_t)row*128 + (i & 127)];
        xsv[i] = v;
    }

    const int d = tid & 63;
    const int fq = tid >> 6;

    // weights for this thread's 2 filters, issued before the barrier
    float w[2][CC][WW];
#pragma unroll
    for (int fi = 0; fi < 2; ++fi) {
        const int f = fq*8 + fh*2 + fi;
#pragma unroll
        for (int c = 0; c < CC; ++c)
#pragma unroll
            for (int j = 0; j < WW; ++j)
                w[fi][c][j] = Wp[((f*CC + c)*WW + j)*DD + d];
    }

    __syncthreads();

    float acc[2][16];
#pragma unroll
    for (int fi = 0; fi < 2; ++fi)
#pragma unroll
        for (int i = 0; i < 16; ++i) acc[fi][i] = 0.f;

#pragma unroll
    for (int rr = 0; rr < 22; ++rr) {
        float xv[CC];
#pragma unroll
        for (int c = 0; c < CC; ++c)
            xv[c] = xs[rr*512 + c*64 + d];
#pragma unroll
        for (int fi = 0; fi < 2; ++fi)
#pragma unroll
            for (int j = 0; j < WW; ++j) {
                const int i = rr - j;          // compile-time guard (full unroll)
                if (i >= 0 && i < 16) {
#pragma unroll
                    for (int c = 0; c < CC; ++c)
                        acc[fi][i] = fmaf(xv[c], w[fi][c][j], acc[fi][i]);
                }
            }
    }

#pragma unroll
    for (int fi = 0; fi < 2; ++fi) {
        const int f = fq*8 + fh*2 + fi;
#pragma unroll
        for (int i = 0; i < 16; ++i) {
            const int h = hb + i;
            const float v = (h < HP) ? acc[fi][i]*qs : 0.f;
            q[((size_t)(n*FF + f)*HPAD + h)*DD + d] = (bf16_t)v;
        }
    }
}

__device__ __forceinline__ float fast_tanh(float x) {
    const float t = __expf(2.f * x);
    return (t - 1.f) / (t + 1.f);
}

// ---------------- fused flash pass (MFMA), 64 h-rows/wave ----------------
// Exact 207.9-us R4 structure (single aq[2][4], Vt dbuf, 1 barrier/tile) with ONE
// added variable: XCD-chunked block swizzle. wg -> (wg&7)*64 + wg/8 (bijective,
// 512%8==0): each XCD owns 16 COMPLETE heads, so a head's 4 h-blocks share one
// L2 copy of q2/V/p1 (round-robin put them on 4 different XCDs: L2 miss -> L3).
// Zero register cost -- isolates the cache-locality variable (R10 conflated it
// with spills: hipcc self-caps at 128 VGPR, aq ping-pong spilled ~90 regs).
template<int MODE>
__global__ __launch_bounds__(256, 2) void flash(
    const bf16_t* __restrict__ q1, const bf16_t* __restrict__ q2,
    const bf16_t* __restrict__ vsrc, bf16_t* __restrict__ p1out,
    float* __restrict__ out)
{
    __shared__ __align__(16) bf16_t Vt[2][64*64];  // V^T tiles [d][p(g)], swizzled

    const int wg = blockIdx.x + 4 * blockIdx.y;    // 512 wgs
    const int swz = (wg & 7) * 64 + (wg >> 3);     // XCD-chunked remap (bijective)
    const int head = swz >> 2;
    const int bx = swz & 3;
    const int n = head >> 5, f = head & 31;
    const int tid = threadIdx.x;
    const int w = tid >> 6;
    const int lane = tid & 63;
    const int lid = lane & 31;
    const int half = lane >> 5;
    const int hb = bx * 256 + w * 64;

    const size_t qoff = (size_t)head * HPAD * DD;
    const int vswz = (lid & 7) ^ (lid >> 2);

    // Vt staging map: thread stages rows g=4gq..4gq+3, cols 4dq..4dq+3
    const int gq = tid >> 4;
    const int dq = tid & 15;
    const int cgb = 4*((gq>>1)&1) + 8*(gq&1) + 16*(gq>>2);   // permuted col base

    const bf16_t* vptr = (MODE == 1) ? vsrc : q2;

    // hoisted per-thread base pointers
    const bf16_t* bp = q1 + qoff + (size_t)(hb + lid)*DD + 8*half;
    const bf16_t* ap = q2 + qoff + (size_t)lid*DD + 8*half;
    const bf16_t* vp = vptr + qoff + (size_t)(4*gq)*DD + 4*dq;

    // Q1 B-fragments, persistent in registers (pre-scaled by QSCALE in conv)
    bf16x8 bq1[2][4];
#pragma unroll
    for (int nt = 0; nt < 2; ++nt)
#pragma unroll
        for (int kt = 0; kt < 4; ++kt)
            bq1[nt][kt] = *(const bf16x8*)&bp[(size_t)(32*nt)*DD + 16*kt];

    // A-fragments for tile 0 (from global)
    bf16x8 aq[2][4];
#pragma unroll
    for (int mt = 0; mt < 2; ++mt)
#pragma unroll
        for (int kt = 0; kt < 4; ++kt)
            aq[mt][kt] = *(const bf16x8*)&ap[(size_t)(32*mt)*DD + 16*kt];

    // V staging regs: tile 0 -> write buffer 0 now; then prefetch tile 1
    bf16x4 rV[4];
#pragma unroll
    for (int i = 0; i < 4; ++i)
        rV[i] = *(const bf16x4*)&vp[(size_t)i*DD];
#pragma unroll
    for (int j = 0; j < 4; ++j) {
        bf16x4 c = { rV[0][j], rV[1][j], rV[2][j], rV[3][j] };
        *(bf16x4*)&Vt[0][vaddr(4*dq + j, cgb)] = c;
    }
#pragma unroll
    for (int i = 0; i < 4; ++i)
        rV[i] = *(const bf16x4*)&vp[(size_t)(64 + i)*DD];

    f32x16 O[2][2] = {};
    float lacc[2] = {0.f, 0.f};

    __syncthreads();                               // Vt[0] ready

    for (int t = 0; t < 16; ++t) {
        const int g0 = t << 6;
        const bf16_t* vtc = Vt[t & 1];

        // stage NEXT tile into the inactive buffer (rV holds tile t+1 data),
        // then prefetch rV for tile t+2 -- overlapped with this tile's compute
        if (t + 1 < 16) {
            bf16_t* vtn = Vt[(t + 1) & 1];
#pragma unroll
            for (int j = 0; j < 4; ++j) {
                bf16x4 c = { rV[0][j], rV[1][j], rV[2][j], rV[3][j] };
                *(bf16x4*)&vtn[vaddr(4*dq + j, cgb)] = c;
            }
            if (t + 2 < 16) {
#pragma unroll
                for (int i = 0; i < 4; ++i)
                    rV[i] = *(const bf16x4*)&vp[(size_t)((t + 2)*64 + i)*DD];
            }
        }

        const bool tail = (g0 + 64 > HP);

#pragma unroll
        for (int mt = 0; mt < 2; ++mt) {
            // ---- S-phase: A-frags from registers (global-prefetched) ----
            f32x16 C[2] = {};
            __builtin_amdgcn_s_setprio(1);
#pragma unroll
            for (int kt = 0; kt < 4; ++kt) {
                C[0] = __builtin_amdgcn_mfma_f32_32x32x16_bf16(aq[mt][kt], bq1[0][kt], C[0], 0,0,0);
                C[1] = __builtin_amdgcn_mfma_f32_32x32x16_bf16(aq[mt][kt], bq1[1][kt], C[1], 0,0,0);
            }
            __builtin_amdgcn_s_setprio(0);
            // reload this mt's A-frags for the NEXT tile (long latency window)
            if (g0 + 64 < HPAD) {
#pragma unroll
                for (int kt = 0; kt < 4; ++kt)
                    aq[mt][kt] = *(const bf16x8*)&ap[(size_t)(g0 + 64 + 32*mt)*DD + 16*kt];
            }
            // ---- exp + pack PV A-frags (no mul: q1 pre-scaled) ----
            bf16x8 af[2][2];
#pragma unroll
            for (int nt = 0; nt < 2; ++nt) {
                float ls = 0.f;
#pragma unroll
                for (int s = 0; s < 16; ++s) {
                    float e = EXP2(C[nt][s]);
                    if (tail) {
                        const int gg = g0 + 32*mt + (s&3) + 8*(s>>2) + 4*half;
                        if (gg >= HP) e = 0.f;
                    }
                    ls += e;
                    af[nt][s>>3][s&7] = (bf16_t)e;
                }
                lacc[nt] += ls;
            }
            // ---- PV: swizzled Vt b128 reads (conflict-free, validated R4) ----
            __builtin_amdgcn_s_setprio(1);
#pragma unroll
            for (int u = 0; u < 2; ++u) {
#pragma unroll
                for (int dt = 0; dt < 2; ++dt) {
                    const int chunk = (4*mt + 2*u + half) ^ vswz;
                    bf16x8 b = *(const bf16x8*)&vtc[(32*dt + lid)*64 + chunk*8];
                    O[0][dt] = __builtin_amdgcn_mfma_f32_32x32x16_bf16(af[0][u], b, O[0][dt], 0,0,0);
                    O[1][dt] = __builtin_amdgcn_mfma_f32_32x32x16_bf16(af[1][u], b, O[1][dt], 0,0,0);
                }
            }
            __builtin_amdgcn_s_setprio(0);
        }
        __syncthreads();                           // vtn writes visible; vtc free
    }

    // ---- epilogue ----
    float linv[2];
#pragma unroll
    for (int nt = 0; nt < 2; ++nt) {
        const float l = lacc[nt] + __shfl_xor(lacc[nt], 32);
        linv[nt] = 1.f / l;
    }
#pragma unroll
    for (int ht = 0; ht < 2; ++ht) {
#pragma unroll
        for (int s = 0; s < 16; ++s) {
            const int R = (s&3) + 8*(s>>2) + 4*half;
            const float li = __shfl(linv[ht], R);
            const int hg = hb + 32*ht + R;
#pragma unroll
            for (int dt = 0; dt < 2; ++dt) {
                const int d = 32*dt + lid;
                const float val = O[ht][dt][s] * li;
                if (hg < HP)
                    out[(((size_t)n*HP + hg)*FF + f)*DD + d] = fast_tanh(val);
                if (MODE == 0)   // zero-pad p1 rows >= HP so pass B stages clean data
                    p1out[qoff + (size_t)hg*DD + d] = (bf16_t)(hg < HP ? val : 0.f);
            }
        }
    }
}

extern "C" void kernel_launch(void* const* d_in, const int* in_sizes, int n_in,
                              void* d_out, int out_size, void* d_ws, size_t ws_size,
                              hipStream_t stream)
{
    const float* prot1 = (const float*)d_in[0];
    const float* prot2 = (const float*)d_in[1];
    const float* Wt    = (const float*)d_in[2];
    float* out = (float*)d_out;

    bf16_t* q1b = (bf16_t*)d_ws;
    bf16_t* q2b = q1b + QWS;
    bf16_t* p1b = q2b + QWS;
    float* Wp   = (float*)(p1b + QWS);

    wprep_kernel<<<dim3(448), 256, 0, stream>>>(Wt, Wp);
    conv_kernel<<<dim3(64, 4, 8), 256, 0, stream>>>(prot1, prot2, Wp, q1b, q2b);
    flash<0><<<dim3(4, NF), 256, 0, stream>>>(q1b, q2b, q2b, p1b, out);
    flash<1><<<dim3(4, NF), 256, 0, stream>>>(q1b, q2b, p1b, p1b, out + QOUT);
}

// Round 13
// 206.083 us; speedup vs baseline: 1.6765x; 1.0151x over previous
//
#include <hip/hip_runtime.h>
#include <math.h>

typedef __bf16 bf16_t;
typedef bf16_t bf16x4 __attribute__((ext_vector_type(4)));
typedef bf16_t bf16x8 __attribute__((ext_vector_type(8)));
typedef float  f32x16 __attribute__((ext_vector_type(16)));

#define HH 1024
#define CC 8
#define DD 64
#define FF 32
#define WW 7
#define HP 1018
#define HPAD 1024
#define NF 128
#define QOUT (NF*HP*DD)
#define QWS ((size_t)NF*HPAD*DD)

#if __has_builtin(__builtin_amdgcn_exp2f)
#define EXP2(x) __builtin_amdgcn_exp2f(x)
#else
#define EXP2(x) __expf((x) * 0.6931471805599453f)
#endif

// q1 is pre-scaled by log2(e)/1018 at conv time, so flash computes exp2(S) directly.
#define QSCALE (1.442695040888963f / 1018.f)

// Lightweight barrier: LDS-visibility only (lgkmcnt), vmcnt loads STAY IN FLIGHT.
// Correct because all cross-wave data flows through LDS (Vt); global loads are
// global->register, per-wave tracked by compiler waits at first use. The default
// __syncthreads() emits s_waitcnt vmcnt(0) which amputates the aq/rV prefetch
// window at every tile boundary (T4 lesson: never drain vmcnt in the main loop).
__device__ __forceinline__ void lds_barrier() {
    asm volatile("s_waitcnt lgkmcnt(0)" ::: "memory");
    __builtin_amdgcn_s_barrier();
    __builtin_amdgcn_sched_barrier(0);   // rule #18: no hoisting across the barrier
}

// Vt: row stride 64 bf16, XOR-swizzled 8-element chunks (validated R4):
//   addr(row, col) = row*64 + (((col>>3) ^ (row&7) ^ ((row>>2)&7))<<3) + (col&7)
__device__ __forceinline__ int vaddr(int row, int col) {
    return row*64 + ((((col>>3) ^ (row&7) ^ ((row>>2)&7)))<<3) + (col&7);
}

// ---------------- W transpose: Wt[f][c][d][j] -> Wp[f][c][j][d] ----------------
__global__ __launch_bounds__(256) void wprep_kernel(
    const float* __restrict__ Wt, float* __restrict__ Wp)
{
    const int idx = blockIdx.x * 256 + threadIdx.x;
    if (idx < FF*CC*DD*WW) {
        const int j = idx % WW;
        int t = idx / WW;
        const int d = t % DD; t /= DD;
        const int c = t % CC;
        const int f = t / CC;
        Wp[((f*CC + c)*WW + j)*DD + d] = Wt[idx];
    }
}

// ---------------- projection (grouped conv) ----------------
// 16-row h-tiles: staged window 22 rows = 45 KB LDS -> 3 blocks/CU.
// xs identity copy [row][c][d]; compute reads xs[row*512 + c*64 + d]: lanes differ
// only in d -> 2 lanes/bank, conflict-free.
// grid (64, 4, 8): z&1 selects input, z>>1 selects filter pair (2 f/thread).
// (Benched as part of the 207.9 us best config.)
__global__ __launch_bounds__(256, 3) void conv_kernel(
    const float* __restrict__ x1, const float* __restrict__ x2,
    const float* __restrict__ Wp, bf16_t* __restrict__ q1, bf16_t* __restrict__ q2)
{
    __shared__ float xs[22*512];
    const int zin = blockIdx.z & 1;
    const int fh = blockIdx.z >> 1;       // 0..3
    const float* x = zin ? x2 : x1;
    bf16_t* q = zin ? q2 : q1;
    const float qs = zin ? 1.f : QSCALE;  // bake softmax scale into q1
    const int n = blockIdx.y;
    const int hb = blockIdx.x * 16;
    const int tid = threadIdx.x;

    const float4* xg = (const float4*)(x + (size_t)n*HH*512);
    float4* xsv = (float4*)xs;
#pragma unroll
    for (int it = 0; it < 11; ++it) {     // 22*128 / 256 = 11
        const int i = it*256 + tid;
        const int row = hb + (i >> 7);
        float4 v = {0.f, 0.f, 0.f, 0.f};
        if (row < HH) v = xg[(size_t)row*128 + (i & 127)];
        xsv[i] = v;
    }

    const int d = tid & 63;
    const int fq = tid >> 6;

    // weights for this thread's 2 filters, issued before the barrier
    float w[2][CC][WW];
#pragma unroll
    for (int fi = 0; fi < 2; ++fi) {
        const int f = fq*8 + fh*2 + fi;
#pragma unroll
        for (int c = 0; c < CC; ++c)
#pragma unroll
            for (int j = 0; j < WW; ++j)
                w[fi][c][j] = Wp[((f*CC + c)*WW + j)*DD + d];
    }

    __syncthreads();

    float acc[2][16];
#pragma unroll
    for (int fi = 0; fi < 2; ++fi)
#pragma unroll
        for (int i = 0; i < 16; ++i) acc[fi][i] = 0.f;

#pragma unroll
    for (int rr = 0; rr < 22; ++rr) {
        float xv[CC];
#pragma unroll
        for (int c = 0; c < CC; ++c)
            xv[c] = xs[rr*512 + c*64 + d];
#pragma unroll
        for (int fi = 0; fi < 2; ++fi)
#pragma unroll
            for (int j = 0; j < WW; ++j) {
                const int i = rr - j;          // compile-time guard (full unroll)
                if (i >= 0 && i < 16) {
#pragma unroll
                    for (int c = 0; c < CC; ++c)
                        acc[fi][i] = fmaf(xv[c], w[fi][c][j], acc[fi][i]);
                }
            }
    }

#pragma unroll
    for (int fi = 0; fi < 2; ++fi) {
        const int f = fq*8 + fh*2 + fi;
#pragma unroll
        for (int i = 0; i < 16; ++i) {
            const int h = hb + i;
            const float v = (h < HP) ? acc[fi][i]*qs : 0.f;
            q[((size_t)(n*FF + f)*HPAD + h)*DD + d] = (bf16_t)v;
        }
    }
}

__device__ __forceinline__ float fast_tanh(float x) {
    const float t = __expf(2.f * x);
    return (t - 1.f) / (t + 1.f);
}

// ---------------- fused flash pass (MFMA), 64 h-rows/wave ----------------
// R4 structure (single aq[2][4], Vt dbuf, 1 barrier/tile) + XCD-chunked swizzle
// (R12: FETCH 41->16.5 MB, time-neutral -> kept for traffic) + ONE new variable:
// lds_barrier() instead of __syncthreads() in the main loop. __syncthreads drains
// vmcnt(0) at every tile boundary, killing the aq/rV prefetch window; the raw
// lgkmcnt-only barrier lets global loads span barriers (T4). Correctness: all
// cross-wave traffic is LDS (lgkm-drained); global loads are per-wave register
// targets with compiler-inserted waits at use.
template<int MODE>
__global__ __launch_bounds__(256, 2) void flash(
    const bf16_t* __restrict__ q1, const bf16_t* __restrict__ q2,
    const bf16_t* __restrict__ vsrc, bf16_t* __restrict__ p1out,
    float* __restrict__ out)
{
    __shared__ __align__(16) bf16_t Vt[2][64*64];  // V^T tiles [d][p(g)], swizzled

    const int wg = blockIdx.x + 4 * blockIdx.y;    // 512 wgs
    const int swz = (wg & 7) * 64 + (wg >> 3);     // XCD-chunked remap (bijective)
    const int head = swz >> 2;
    const int bx = swz & 3;
    const int n = head >> 5, f = head & 31;
    const int tid = threadIdx.x;
    const int w = tid >> 6;
    const int lane = tid & 63;
    const int lid = lane & 31;
    const int half = lane >> 5;
    const int hb = bx * 256 + w * 64;

    const size_t qoff = (size_t)head * HPAD * DD;
    const int vswz = (lid & 7) ^ (lid >> 2);

    // Vt staging map: thread stages rows g=4gq..4gq+3, cols 4dq..4dq+3
    const int gq = tid >> 4;
    const int dq = tid & 15;
    const int cgb = 4*((gq>>1)&1) + 8*(gq&1) + 16*(gq>>2);   // permuted col base

    const bf16_t* vptr = (MODE == 1) ? vsrc : q2;

    // hoisted per-thread base pointers
    const bf16_t* bp = q1 + qoff + (size_t)(hb + lid)*DD + 8*half;
    const bf16_t* ap = q2 + qoff + (size_t)lid*DD + 8*half;
    const bf16_t* vp = vptr + qoff + (size_t)(4*gq)*DD + 4*dq;

    // Q1 B-fragments, persistent in registers (pre-scaled by QSCALE in conv)
    bf16x8 bq1[2][4];
#pragma unroll
    for (int nt = 0; nt < 2; ++nt)
#pragma unroll
        for (int kt = 0; kt < 4; ++kt)
            bq1[nt][kt] = *(const bf16x8*)&bp[(size_t)(32*nt)*DD + 16*kt];

    // A-fragments for tile 0 (from global)
    bf16x8 aq[2][4];
#pragma unroll
    for (int mt = 0; mt < 2; ++mt)
#pragma unroll
        for (int kt = 0; kt < 4; ++kt)
            aq[mt][kt] = *(const bf16x8*)&ap[(size_t)(32*mt)*DD + 16*kt];

    // V staging regs: tile 0 -> write buffer 0 now; then prefetch tile 1
    bf16x4 rV[4];
#pragma unroll
    for (int i = 0; i < 4; ++i)
        rV[i] = *(const bf16x4*)&vp[(size_t)i*DD];
#pragma unroll
    for (int j = 0; j < 4; ++j) {
        bf16x4 c = { rV[0][j], rV[1][j], rV[2][j], rV[3][j] };
        *(bf16x4*)&Vt[0][vaddr(4*dq + j, cgb)] = c;
    }
#pragma unroll
    for (int i = 0; i < 4; ++i)
        rV[i] = *(const bf16x4*)&vp[(size_t)(64 + i)*DD];

    f32x16 O[2][2] = {};
    float lacc[2] = {0.f, 0.f};

    lds_barrier();                                 // Vt[0] ready

    for (int t = 0; t < 16; ++t) {
        const int g0 = t << 6;
        const bf16_t* vtc = Vt[t & 1];

        // stage NEXT tile into the inactive buffer (rV holds tile t+1 data),
        // then prefetch rV for tile t+2 -- overlapped with this tile's compute
        if (t + 1 < 16) {
            bf16_t* vtn = Vt[(t + 1) & 1];
#pragma unroll
            for (int j = 0; j < 4; ++j) {
                bf16x4 c = { rV[0][j], rV[1][j], rV[2][j], rV[3][j] };
                *(bf16x4*)&vtn[vaddr(4*dq + j, cgb)] = c;
            }
            if (t + 2 < 16) {
#pragma unroll
                for (int i = 0; i < 4; ++i)
                    rV[i] = *(const bf16x4*)&vp[(size_t)((t + 2)*64 + i)*DD];
            }
        }

        const bool tail = (g0 + 64 > HP);

#pragma unroll
        for (int mt = 0; mt < 2; ++mt) {
            // ---- S-phase: A-frags from registers (global-prefetched) ----
            f32x16 C[2] = {};
            __builtin_amdgcn_s_setprio(1);
#pragma unroll
            for (int kt = 0; kt < 4; ++kt) {
                C[0] = __builtin_amdgcn_mfma_f32_32x32x16_bf16(aq[mt][kt], bq1[0][kt], C[0], 0,0,0);
                C[1] = __builtin_amdgcn_mfma_f32_32x32x16_bf16(aq[mt][kt], bq1[1][kt], C[1], 0,0,0);
            }
            __builtin_amdgcn_s_setprio(0);
            // reload this mt's A-frags for the NEXT tile (now genuinely long-lived:
            // these loads survive the tile barrier un-drained)
            if (g0 + 64 < HPAD) {
#pragma unroll
                for (int kt = 0; kt < 4; ++kt)
                    aq[mt][kt] = *(const bf16x8*)&ap[(size_t)(g0 + 64 + 32*mt)*DD + 16*kt];
            }
            // ---- exp + pack PV A-frags (no mul: q1 pre-scaled) ----
            bf16x8 af[2][2];
#pragma unroll
            for (int nt = 0; nt < 2; ++nt) {
                float ls = 0.f;
#pragma unroll
                for (int s = 0; s < 16; ++s) {
                    float e = EXP2(C[nt][s]);
                    if (tail) {
                        const int gg = g0 + 32*mt + (s&3) + 8*(s>>2) + 4*half;
                        if (gg >= HP) e = 0.f;
                    }
                    ls += e;
                    af[nt][s>>3][s&7] = (bf16_t)e;
                }
                lacc[nt] += ls;
            }
            // ---- PV: swizzled Vt b128 reads (conflict-free, validated R4) ----
            __builtin_amdgcn_s_setprio(1);
#pragma unroll
            for (int u = 0; u < 2; ++u) {
#pragma unroll
                for (int dt = 0; dt < 2; ++dt) {
                    const int chunk = (4*mt + 2*u + half) ^ vswz;
                    bf16x8 b = *(const bf16x8*)&vtc[(32*dt + lid)*64 + chunk*8];
                    O[0][dt] = __builtin_amdgcn_mfma_f32_32x32x16_bf16(af[0][u], b, O[0][dt], 0,0,0);
                    O[1][dt] = __builtin_amdgcn_mfma_f32_32x32x16_bf16(af[1][u], b, O[1][dt], 0,0,0);
                }
            }
            __builtin_amdgcn_s_setprio(0);
        }
        lds_barrier();                             // vtn writes visible; vtc free
    }

    // ---- epilogue ----
    float linv[2];
#pragma unroll
    for (int nt = 0; nt < 2; ++nt) {
        const float l = lacc[nt] + __shfl_xor(lacc[nt], 32);
        linv[nt] = 1.f / l;
    }
#pragma unroll
    for (int ht = 0; ht < 2; ++ht) {
#pragma unroll
        for (int s = 0; s < 16; ++s) {
            const int R = (s&3) + 8*(s>>2) + 4*half;
            const float li = __shfl(linv[ht], R);
            const int hg = hb + 32*ht + R;
#pragma unroll
            for (int dt = 0; dt < 2; ++dt) {
                const int d = 32*dt + lid;
                const float val = O[ht][dt][s] * li;
                if (hg < HP)
                    out[(((size_t)n*HP + hg)*FF + f)*DD + d] = fast_tanh(val);
                if (MODE == 0)   // zero-pad p1 rows >= HP so pass B stages clean data
                    p1out[qoff + (size_t)hg*DD + d] = (bf16_t)(hg < HP ? val : 0.f);
            }
        }
    }
}

extern "C" void kernel_launch(void* const* d_in, const int* in_sizes, int n_in,
                              void* d_out, int out_size, void* d_ws, size_t ws_size,
                              hipStream_t stream)
{
    const float* prot1 = (const float*)d_in[0];
    const float* prot2 = (const float*)d_in[1];
    const float* Wt    = (const float*)d_in[2];
    float* out = (float*)d_out;

    bf16_t* q1b = (bf16_t*)d_ws;
    bf16_t* q2b = q1b + QWS;
    bf16_t* p1b = q2b + QWS;
    float* Wp   = (float*)(p1b + QWS);

    wprep_kernel<<<dim3(448), 256, 0, stream>>>(Wt, Wp);
    conv_kernel<<<dim3(64, 4, 8), 256, 0, stream>>>(prot1, prot2, Wp, q1b, q2b);
    flash<0><<<dim3(4, NF), 256, 0, stream>>>(q1b, q2b, q2b, p1b, out);
    flash<1><<<dim3(4, NF), 256, 0, stream>>>(q1b, q2b, p1b, p1b, out + QOUT);
}